// Round 9
// baseline (322.913 us; speedup 1.0000x reference)
//
#include <hip/hip_runtime.h>

typedef __bf16 bf16;
typedef __bf16 bf16x8 __attribute__((ext_vector_type(8)));
typedef float  f32x4  __attribute__((ext_vector_type(4)));

// Problem constants
#define NSPEC   512          // 256 pairs * 2
#define BOUT    9999         // GROUPS*3
#define K0A     10240        // BOUT padded to 16*10*64 (ksplit*kiters*BK)
#define N00     1024         // 1000 padded
#define KSPLIT0 16
#define PREPREPS 8           // R9 probe: prep body x8 (idempotent) -> PMC visible in top-5
                             // slope: prep = top5_dur/8; reduce/t1/t2 probed via launch loop

// async global->LDS, 16B per lane; lds base must be wave-uniform (HW adds lane*16)
__device__ __forceinline__ void gload_lds16(const bf16* g, bf16* l) {
    auto* gp = reinterpret_cast<const __attribute__((address_space(1))) unsigned int*>(
        reinterpret_cast<uintptr_t>(g));
    auto* lp = reinterpret_cast<__attribute__((address_space(3))) unsigned int*>(
        reinterpret_cast<uintptr_t>(l));
    __builtin_amdgcn_global_load_lds(gp, lp, 16, 0, 0);
}

// ---------------- transpose helper: 64(n) x 64(k) tile, 512 threads (R5-verified) ----------------
__device__ __forceinline__ void transpose_tile64(const float* __restrict__ src,
                                                 bf16* __restrict__ dst,
                                                 int K, int N, int K0,
                                                 float* tile, int bx, int by) {
    int n0 = bx * 64, k0 = by * 64;
    int t = threadIdx.x;
    {
        int kr = t >> 3, fc = (t & 7) * 8;           // 64 k-rows x 64 n-cols, 8 f32/thread
        int gk = k0 + kr;
#pragma unroll
        for (int h = 0; h < 2; ++h) {
            int gn = n0 + fc + h * 4;
            float4 v;
            if (gk < K && gn + 3 < N) {              // interior fast path (N%4==0 -> aligned)
                v = *reinterpret_cast<const float4*>(src + (size_t)gk * N + gn);
            } else {
                v.x = (gk < K && gn + 0 < N) ? src[(size_t)gk * N + gn + 0] : 0.f;
                v.y = (gk < K && gn + 1 < N) ? src[(size_t)gk * N + gn + 1] : 0.f;
                v.z = (gk < K && gn + 2 < N) ? src[(size_t)gk * N + gn + 2] : 0.f;
                v.w = (gk < K && gn + 3 < N) ? src[(size_t)gk * N + gn + 3] : 0.f;
            }
            tile[kr * 65 + fc + h * 4 + 0] = v.x;
            tile[kr * 65 + fc + h * 4 + 1] = v.y;
            tile[kr * 65 + fc + h * 4 + 2] = v.z;
            tile[kr * 65 + fc + h * 4 + 3] = v.w;
        }
    }
    __syncthreads();
    {
        int nr = t >> 3, kc = (t & 7) * 8;           // 64 n-rows x 64 k-cols, 8 bf16/thread
        bf16 v[8];
#pragma unroll
        for (int e = 0; e < 8; ++e) v[e] = (bf16)tile[(kc + e) * 65 + nr];  // 2-way banks: free
        *(uint4*)&dst[(size_t)(n0 + nr) * K0 + k0 + kc] = *(uint4*)v;       // 16 B store
    }
}

// ---------------- mega-prep (R5-exact body) x PREPREPS internal reps ----------------
// Block map (3665 blocks): w0 2560 | w1 224 | w2 224 | we 112 | build_A 512 | pads 32 | psums 1
__global__ __launch_bounds__(512) void prep_all(const float* __restrict__ mz,
                                                const float* __restrict__ inten,
                                                const float* __restrict__ bw,
                                                const float* __restrict__ bb,
                                                const float* __restrict__ w0,
                                                const float* __restrict__ w1,
                                                const float* __restrict__ w2,
                                                const float* __restrict__ we,
                                                bf16* __restrict__ A,
                                                bf16* __restrict__ B0t,
                                                bf16* __restrict__ B1t,
                                                bf16* __restrict__ B2t,
                                                bf16* __restrict__ BEt,
                                                bf16* __restrict__ H1b,
                                                bf16* __restrict__ H2b,
                                                float* __restrict__ psums) {
    __shared__ float smem[K0A];    // 40 KB: sacc for build_A, tile[64*65] for transposes
    int b = blockIdx.x;
    for (int rep = 0; rep < PREPREPS; ++rep) {
        if (b < 2560) {                       // w0 -> B0t (1024 x 10240): 16(n) x 160(k) tiles
            transpose_tile64(w0, B0t, BOUT, 1000, K0A, smem, b & 15, b >> 4);
        } else if (b < 2784) {                // w1 -> B1t (896 x 1024): 14 x 16
            int r = b - 2560;
            transpose_tile64(w1, B1t, 1000, 800, 1024, smem, r % 14, r / 14);
        } else if (b < 3008) {                // w2 -> B2t (896 x 1024): 14 x 16
            int r = b - 2784;
            transpose_tile64(w2, B2t, 800, 800, 1024, smem, r % 14, r / 14);
        } else if (b < 3120) {                // we -> BEt (448 x 1024): 7 x 16
            int r = b - 3008;
            transpose_tile64(we, BEt, 800, 400, 1024, smem, r % 7, r / 7);
        } else if (b < 3632) {                // build_A: one block per spectrum
            const int spec = b - 3120;
            const int t = threadIdx.x;
#pragma unroll
            for (int i = 0; i < 5; ++i)
                *(float4*)&smem[(i * 512 + t) * 4] = float4{0.f, 0.f, 0.f, 0.f};
            __syncthreads();
            {
                float m = mz[(size_t)spec * 512 + t];
                float v = inten[(size_t)spec * 512 + t];
                bool mask = (m >= 0.0f) && (m < 1000.0f);
                int idx = (int)(m / 0.01f);       // IEEE div + trunc, matches astype(int32)
                idx = min(max(idx, 0), 99999);
                if (mask && idx < 99990) {
                    int g = idx / 30;
                    float val = sqrtf(v);         // inten ** 0.5
                    const float* w = bw + (size_t)idx * 3;
                    atomicAdd(&smem[g * 3 + 0], val * w[0]);
                    atomicAdd(&smem[g * 3 + 1], val * w[1]);
                    atomicAdd(&smem[g * 3 + 2], val * w[2]);
                }
            }
            __syncthreads();
            bf16* Arow = A + (size_t)spec * K0A;
#pragma unroll
            for (int i = 0; i < 5; ++i) {
                int c = (i * 512 + t) * 4;
                float4 s = *(const float4*)&smem[c];
                bf16 o[4];
                o[0] = (bf16)((c + 0 < BOUT) ? bb[c + 0] + s.x : 0.f);
                o[1] = (bf16)((c + 1 < BOUT) ? bb[c + 1] + s.y : 0.f);
                o[2] = (bf16)((c + 2 < BOUT) ? bb[c + 2] + s.z : 0.f);
                o[3] = (bf16)((c + 3 < BOUT) ? bb[c + 3] + s.w : 0.f);
                *(ushort4*)&Arow[c] = *(ushort4*)o;
            }
        } else if (b < 3664) {                // zero K-pad cols 896..1023 of H1b/H2b
            int idx = b - 3632;               // 0..31
            bf16* H = (idx < 16) ? H1b : H2b;
            int sub = idx & 15;
            int t = threadIdx.x;
            int row = sub * 32 + (t >> 4);
            int col = 896 + (t & 15) * 8;
            *(uint4*)&H[(size_t)row * 1024 + col] = uint4{0u, 0u, 0u, 0u};
        } else {                              // zero cosine accumulators + done counter
            for (int i = threadIdx.x; i < 1024; i += 512) psums[i] = 0.f;
        }
        __syncthreads();   // rep boundary: LDS tile/sacc reuse safety
    }
}

// ---------------- GEMM0 (R5-exact, single rep) ----------------
__global__ __launch_bounds__(512) void gemm0_splitk(const bf16* __restrict__ A,
                                                    const bf16* __restrict__ Bt,
                                                    bf16* __restrict__ Cslab) {
    constexpr int K0 = K0A, KITERS = 10, BK = 64;
    __shared__ __align__(16) bf16 As[2][128 * BK];   // 16 KB each buf
    __shared__ __align__(16) bf16 Bs[2][128 * BK];   // 16 KB each buf
    const int bid = blockIdx.x;
    const int kp = bid & 15;                  // XCD = bid%8 hosts kp, kp+8
    const int tile = bid >> 4;                // 0..31
    const int mt = tile & 3, nt = tile >> 2;  // 4 x 8
    const int tid = threadIdx.x, wave = tid >> 6, lane = tid & 63;
    const int wm = wave & 1, wn = wave >> 1;  // 2x4 wave grid: 64m x 32n per wave
    const int lrow = lane & 15, quad = lane >> 4;

    const bf16* Ag = A  + (size_t)(mt * 128) * K0 + kp * (KITERS * BK);
    const bf16* Bg = Bt + (size_t)(nt * 128) * K0 + kp * (KITERS * BK);

    auto stage = [&](int buf, int kk) {
        const int k = kk * BK;
        const int lr = lane >> 3;
        const int lch = lane & 7;
#pragma unroll
        for (int j = 0; j < 2; ++j) {                  // A: 128 rows in 2 calls/wave
            int row0 = j * 64 + wave * 8;
            int row = row0 + lr;
            int ch  = lch ^ (row & 7);
            gload_lds16(Ag + (size_t)row * K0 + k + ch * 8, &As[buf][row0 * BK]);
        }
#pragma unroll
        for (int j = 0; j < 2; ++j) {                  // B: 128 rows in 2 calls/wave
            int row0 = j * 64 + wave * 8;
            int row = row0 + lr;
            int ch  = lch ^ (row & 7);
            gload_lds16(Bg + (size_t)row * K0 + k + ch * 8, &Bs[buf][row0 * BK]);
        }
    };

    f32x4 acc[4][2] = {};
    stage(0, 0);
    for (int kk = 0; kk < KITERS; ++kk) {
        const int cur = kk & 1;
        __syncthreads();                      // buf[cur] drained (vmcnt0 at barrier)
        if (kk + 1 < KITERS) stage(cur ^ 1, kk + 1);  // prefetch overlaps compute
#pragma unroll
        for (int ks = 0; ks < 2; ++ks) {
            bf16x8 af[4], bfr[2];
            const int c = ks * 4 + quad;
#pragma unroll
            for (int im = 0; im < 4; ++im) {
                int r = wm * 64 + im * 16 + lrow;
                af[im] = *(const bf16x8*)&As[cur][r * BK + ((c ^ (r & 7)) << 3)];
            }
#pragma unroll
            for (int in = 0; in < 2; ++in) {
                int r = wn * 32 + in * 16 + lrow;
                bfr[in] = *(const bf16x8*)&Bs[cur][r * BK + ((c ^ (r & 7)) << 3)];
            }
#pragma unroll
            for (int im = 0; im < 4; ++im)
#pragma unroll
                for (int in = 0; in < 2; ++in)
                    acc[im][in] = __builtin_amdgcn_mfma_f32_16x16x32_bf16(af[im], bfr[in], acc[im][in], 0, 0, 0);
        }
    }
    // bf16 partial stores into this kp's slab — no atomics, no fences
    bf16* C = Cslab + (size_t)kp * (NSPEC * N00);
#pragma unroll
    for (int im = 0; im < 4; ++im) {
        int row0 = mt * 128 + wm * 64 + im * 16 + quad * 4;
#pragma unroll
        for (int in = 0; in < 2; ++in) {
            int col = nt * 128 + wn * 32 + in * 16 + lrow;
#pragma unroll
            for (int r = 0; r < 4; ++r)
                C[(size_t)(row0 + r) * N00 + col] = (bf16)acc[im][in][r];
        }
    }
}

// ---------------- reduce 16 bf16 slabs + bias + relu + bf16 cvt (R5-exact) ----------------
__global__ __launch_bounds__(256) void reduce_bias_relu(const bf16* __restrict__ Cslab,
                                                        const float* __restrict__ b0,
                                                        bf16* __restrict__ H0b) {
    int idx = blockIdx.x * 256 + threadIdx.x;     // 65536 chunks of 8
    int r = idx >> 7, c = (idx & 127) * 8;
    float s[8] = {};
#pragma unroll
    for (int kp = 0; kp < KSPLIT0; ++kp) {
        bf16x8 v = *(const bf16x8*)&Cslab[(size_t)kp * (NSPEC * N00) + (size_t)r * N00 + c];
#pragma unroll
        for (int j = 0; j < 8; ++j) s[j] += (float)v[j];
    }
    bf16 o[8];
#pragma unroll
    for (int j = 0; j < 8; ++j)
        o[j] = (bf16)fmaxf(s[j] + ((c + j < 1000) ? b0[c + j] : 0.f), 0.f);
    *(uint4*)&H0b[(size_t)r * N00 + c] = *(uint4*)o;
}

// ---------------- tail GEMM (R5-exact): 32x64 tiles, BK=256, full-K per wave ----------------
template <bool LAST>
__global__ __launch_bounds__(512) void gemm_tail(const bf16* __restrict__ A,
                                                 const bf16* __restrict__ Bt,
                                                 const float* __restrict__ bias,
                                                 bf16* __restrict__ Ob,
                                                 float* __restrict__ psums,
                                                 unsigned* __restrict__ done,
                                                 float* __restrict__ out,
                                                 int Nreal, int ntiles) {
    constexpr int BK = 256, KITERS = 4;
    __shared__ __align__(16) bf16 As[2][32 * BK];   // 16 KB each
    __shared__ __align__(16) bf16 Bs[2][64 * BK];   // 32 KB each
    __shared__ unsigned lastf;
    const int bid = blockIdx.x;
    const int mt = bid / ntiles, nt = bid % ntiles;
    const int tid = threadIdx.x, wave = tid >> 6, lane = tid & 63;
    const int wm = wave & 1, wn = wave >> 1;        // 2(m) x 4(n) waves over 32x64
    const int lrow = lane & 15, quad = lane >> 4;

    const bf16* Ag = A  + (size_t)(mt * 32) * 1024;
    const bf16* Bg = Bt + (size_t)(nt * 64) * 1024;

    auto stage = [&](int buf, int kk) {
        const int k = kk * BK;
#pragma unroll
        for (int j = 0; j < 2; ++j) {                  // A: 32 rows, 2 calls/wave
            int row0 = (wave + j * 8) * 2;
            int row = row0 + (lane >> 5);
            int ch  = (lane & 31) ^ (row & 31);        // swizzled source chunk
            gload_lds16(Ag + (size_t)row * 1024 + k + ch * 8, &As[buf][row0 * BK]);
        }
#pragma unroll
        for (int j = 0; j < 4; ++j) {                  // B: 64 rows, 4 calls/wave
            int row0 = (wave + j * 8) * 2;
            int row = row0 + (lane >> 5);
            int ch  = (lane & 31) ^ (row & 31);
            gload_lds16(Bg + (size_t)row * 1024 + k + ch * 8, &Bs[buf][row0 * BK]);
        }
    };

    f32x4 acc = {};
    stage(0, 0);
    for (int kk = 0; kk < KITERS; ++kk) {
        const int cur = kk & 1;
        __syncthreads();
        if (kk + 1 < KITERS) stage(cur ^ 1, kk + 1);
#pragma unroll
        for (int ks = 0; ks < 8; ++ks) {               // full K: 8 MFMA per iter per wave
            int ra = wm * 16 + lrow, rb = wn * 16 + lrow;
            int c = ks * 4 + quad;                     // c 0..31 covers BK=256
            bf16x8 af  = *(const bf16x8*)&As[cur][ra * BK + ((c ^ (ra & 31)) << 3)];
            bf16x8 bfr = *(const bf16x8*)&Bs[cur][rb * BK + ((c ^ (rb & 31)) << 3)];
            acc = __builtin_amdgcn_mfma_f32_16x16x32_bf16(af, bfr, acc, 0, 0, 0);
        }
    }
    // epilogue: each wave owns quadrant (wm, wn) — exactly-once coverage of 32x64
    {
        int row0 = mt * 32 + wm * 16 + quad * 4;
        int col  = nt * 64 + wn * 16 + lrow;
        if (!LAST) {
            float bv = (col < Nreal) ? bias[col] : 0.f;
#pragma unroll
            for (int r = 0; r < 4; ++r)
                Ob[(size_t)(row0 + r) * 1024 + col] = (bf16)fmaxf(acc[r] + bv, 0.f);
        } else {
            bool valid = (col < 400);
            float bv = valid ? bias[col] : 0.f;
            float v[4];
#pragma unroll
            for (int r = 0; r < 4; ++r) v[r] = valid ? (acc[r] + bv) : 0.f;
            int p0 = row0 >> 1;                        // pairs p0, p0+1 (row0 even)
            float sums[6] = {v[0] * v[1], v[0] * v[0], v[1] * v[1],
                             v[2] * v[3], v[2] * v[2], v[3] * v[3]};
#pragma unroll
            for (int off = 1; off < 16; off <<= 1)
#pragma unroll
                for (int s = 0; s < 6; ++s) sums[s] += __shfl_xor(sums[s], off);
            if (lrow == 0) {
#pragma unroll
                for (int s = 0; s < 3; ++s) {
                    atomicAdd(&psums[(p0 + 0) * 3 + s], sums[s]);
                    atomicAdd(&psums[(p0 + 1) * 3 + s], sums[3 + s]);
                }
            }
        }
    }
    if (LAST) {
        // last-finisher cosine finalize (112 blocks)
        __syncthreads();
        if (tid == 0) {
            __threadfence();               // release: psum atomics ordered before counter add
            unsigned old = __hip_atomic_fetch_add(done, 1u, __ATOMIC_ACQ_REL,
                                                  __HIP_MEMORY_SCOPE_AGENT);
            lastf = (old == 111u) ? 1u : 0u;
        }
        __syncthreads();
        if (lastf && tid < 256) {
            float d  = __hip_atomic_load(&psums[tid * 3 + 0], __ATOMIC_RELAXED, __HIP_MEMORY_SCOPE_AGENT);
            float s1 = __hip_atomic_load(&psums[tid * 3 + 1], __ATOMIC_RELAXED, __HIP_MEMORY_SCOPE_AGENT);
            float s2 = __hip_atomic_load(&psums[tid * 3 + 2], __ATOMIC_RELAXED, __HIP_MEMORY_SCOPE_AGENT);
            float n1 = fmaxf(sqrtf(s1), 1e-6f);
            float n2 = fmaxf(sqrtf(s2), 1e-6f);
            out[tid] = d / (n1 * n2);
        }
    }
}

extern "C" void kernel_launch(void* const* d_in, const int* in_sizes, int n_in,
                              void* d_out, int out_size, void* d_ws, size_t ws_size,
                              hipStream_t stream) {
    const float* mz    = (const float*)d_in[0];
    const float* inten = (const float*)d_in[1];
    const float* bw    = (const float*)d_in[2];
    const float* bb    = (const float*)d_in[3];
    const float* w0    = (const float*)d_in[4];
    const float* b0    = (const float*)d_in[5];
    const float* w1    = (const float*)d_in[6];
    const float* b1    = (const float*)d_in[7];
    const float* w2    = (const float*)d_in[8];
    const float* b2    = (const float*)d_in[9];
    const float* we    = (const float*)d_in[10];
    const float* be    = (const float*)d_in[11];
    float* out = (float*)d_out;

    char* ws = (char*)d_ws;
    size_t off = 0;
    auto alloc = [&](size_t bytes) { char* p = ws + off; off += (bytes + 255) & ~(size_t)255; return p; };
    bf16*  A     = (bf16*) alloc((size_t)NSPEC * K0A * 2);
    bf16*  B0t   = (bf16*) alloc((size_t)N00 * K0A * 2);
    bf16*  B1t   = (bf16*) alloc((size_t)896 * 1024 * 2);
    bf16*  B2t   = (bf16*) alloc((size_t)896 * 1024 * 2);
    bf16*  BEt   = (bf16*) alloc((size_t)448 * 1024 * 2);
    bf16*  Cslab = (bf16*) alloc((size_t)KSPLIT0 * NSPEC * N00 * 2);   // 16 MB
    bf16*  H0b   = (bf16*) alloc((size_t)NSPEC * 1024 * 2);
    bf16*  H1b   = (bf16*) alloc((size_t)NSPEC * 1024 * 2);
    bf16*  H2b   = (bf16*) alloc((size_t)NSPEC * 1024 * 2);
    float* psums = (float*)alloc(1024 * 4);        // 768 psums + done counter + pad
    unsigned* done = (unsigned*)(psums + 768);

    // R9 budget probe: prep x8 internal (PMC row in top-5); reduce/t1/t2 x8 via dispatch
    // loop (DCE-proof); gemm0/t3 single. dur = 162.3 + 7*(prep+reduce+t1+t2).
    prep_all<<<3665, 512, 0, stream>>>(mz, inten, bw, bb, w0, w1, w2, we,
                                       A, B0t, B1t, B2t, BEt, H1b, H2b, psums);
    gemm0_splitk<<<512, 512, 0, stream>>>(A, B0t, Cslab);
    for (int r = 0; r < 8; ++r)
        reduce_bias_relu<<<256, 256, 0, stream>>>(Cslab, b0, H0b);
    for (int r = 0; r < 8; ++r)
        gemm_tail<false><<<224, 512, 0, stream>>>(H0b, B1t, b1, H1b, nullptr, nullptr, nullptr, 800, 14);
    for (int r = 0; r < 8; ++r)
        gemm_tail<false><<<224, 512, 0, stream>>>(H1b, B2t, b2, H2b, nullptr, nullptr, nullptr, 800, 14);
    gemm_tail<true ><<<112, 512, 0, stream>>>(H2b, BEt, be, nullptr, psums, done, out, 400, 7);
}

// Round 10
// 168.984 us; speedup vs baseline: 1.9109x; 1.9109x over previous
//
#include <hip/hip_runtime.h>

typedef __bf16 bf16;
typedef __bf16 bf16x8 __attribute__((ext_vector_type(8)));
typedef float  f32x4  __attribute__((ext_vector_type(4)));

// Problem constants
#define NSPEC   512          // 256 pairs * 2
#define BOUT    9999         // GROUPS*3
#define K0A     10240        // BOUT padded to 16*10*64 (ksplit*kiters*BK)
#define N00     1024         // 1000 padded
#define KSPLIT0 16

// async global->LDS, 16B per lane; lds base must be wave-uniform (HW adds lane*16)
__device__ __forceinline__ void gload_lds16(const bf16* g, bf16* l) {
    auto* gp = reinterpret_cast<const __attribute__((address_space(1))) unsigned int*>(
        reinterpret_cast<uintptr_t>(g));
    auto* lp = reinterpret_cast<__attribute__((address_space(3))) unsigned int*>(
        reinterpret_cast<uintptr_t>(l));
    __builtin_amdgcn_global_load_lds(gp, lp, 16, 0, 0);
}

// ---------------- transpose helper: 64(n) x 64(k) tile, 256 threads ----------------
// R10: 256-thread variant (16 elems/thread both phases). tile = f32[64][65] = 16.6 KB.
// Bank audit: load writes bank=(t>>2)+16*(t&3)%32 -> 2-way (free, m136); store reads
// per-e bank=(t>>2)+16*(t&1 of t&3)+e -> 2-way (free).
__device__ __forceinline__ void transpose_tile64(const float* __restrict__ src,
                                                 bf16* __restrict__ dst,
                                                 int K, int N, int K0,
                                                 float* tile, int bx, int by) {
    int n0 = bx * 64, k0 = by * 64;
    int t = threadIdx.x;
    {
        int kr = t >> 2, fc = (t & 3) * 16;          // 64 k-rows x 64 n-cols, 16 f32/thread
        int gk = k0 + kr;
#pragma unroll
        for (int h = 0; h < 4; ++h) {
            int gn = n0 + fc + h * 4;
            float4 v;
            if (gk < K && gn + 3 < N) {              // interior fast path (N%4==0 -> aligned)
                v = *reinterpret_cast<const float4*>(src + (size_t)gk * N + gn);
            } else {
                v.x = (gk < K && gn + 0 < N) ? src[(size_t)gk * N + gn + 0] : 0.f;
                v.y = (gk < K && gn + 1 < N) ? src[(size_t)gk * N + gn + 1] : 0.f;
                v.z = (gk < K && gn + 2 < N) ? src[(size_t)gk * N + gn + 2] : 0.f;
                v.w = (gk < K && gn + 3 < N) ? src[(size_t)gk * N + gn + 3] : 0.f;
            }
            tile[kr * 65 + fc + h * 4 + 0] = v.x;
            tile[kr * 65 + fc + h * 4 + 1] = v.y;
            tile[kr * 65 + fc + h * 4 + 2] = v.z;
            tile[kr * 65 + fc + h * 4 + 3] = v.w;
        }
    }
    __syncthreads();
    {
        int nr = t >> 2, kc = (t & 3) * 16;          // 64 n-rows x 64 k-cols, 16 bf16/thread
        bf16 v[16];
#pragma unroll
        for (int e = 0; e < 16; ++e) v[e] = (bf16)tile[(kc + e) * 65 + nr];
        *(uint4*)&dst[(size_t)(n0 + nr) * K0 + k0 + kc + 0] = *(uint4*)&v[0];
        *(uint4*)&dst[(size_t)(n0 + nr) * K0 + k0 + kc + 8] = *(uint4*)&v[8];
    }
}

// ---------------- mega-prep v2: 256 thr, 20 KB LDS -> 8 blocks/CU (was 4) ----------------
// R9 PMC: prep was occupancy/rounds-bound (VALUBusy 13%, HBM 20%, Occ 41%).
// 512-thr blocks capped at 4/CU by the 32-wave limit AND 40 KB LDS. 256-thr + 20 KB
// doubles concurrency; 3.6 scheduling rounds -> 2.0. build_A splits per spectrum into
// 2 half-group-range blocks (split at group 1668 = col 5004: group- and 4-aligned;
// h=1 guard l<4995 lands exactly on BOUT).
// Block map (4177): w0 2560 | w1 224 | w2 224 | we 112 | build_A 1024 | pads 32 | psums 1
__global__ __launch_bounds__(256) void prep_all(const float* __restrict__ mz,
                                                const float* __restrict__ inten,
                                                const float* __restrict__ bw,
                                                const float* __restrict__ bb,
                                                const float* __restrict__ w0,
                                                const float* __restrict__ w1,
                                                const float* __restrict__ w2,
                                                const float* __restrict__ we,
                                                bf16* __restrict__ A,
                                                bf16* __restrict__ B0t,
                                                bf16* __restrict__ B1t,
                                                bf16* __restrict__ B2t,
                                                bf16* __restrict__ BEt,
                                                bf16* __restrict__ H1b,
                                                bf16* __restrict__ H2b,
                                                float* __restrict__ psums) {
    __shared__ float smem[5120];   // 20 KB: tile[64*65]=16.6K for transposes; 5004 for build_A
    int b = blockIdx.x;
    if (b < 2560) {                       // w0 -> B0t (1024 x 10240): 16(n) x 160(k) tiles
        transpose_tile64(w0, B0t, BOUT, 1000, K0A, smem, b & 15, b >> 4);
    } else if (b < 2784) {                // w1 -> B1t (896 x 1024): 14 x 16
        int r = b - 2560;
        transpose_tile64(w1, B1t, 1000, 800, 1024, smem, r % 14, r / 14);
    } else if (b < 3008) {                // w2 -> B2t (896 x 1024): 14 x 16
        int r = b - 2784;
        transpose_tile64(w2, B2t, 800, 800, 1024, smem, r % 14, r / 14);
    } else if (b < 3120) {                // we -> BEt (448 x 1024): 7 x 16
        int r = b - 3008;
        transpose_tile64(we, BEt, 800, 400, 1024, smem, r % 7, r / 7);
    } else if (b < 4144) {                // build_A: 2 blocks per spectrum (group-range halves)
        const int spec = (b - 3120) >> 1;
        const int h    = (b - 3120) & 1;
        const int g0   = h ? 1668 : 0;
        const int ng   = h ? (3333 - 1668) : 1668;   // 1665 : 1668 groups
        const int c0   = g0 * 3;                     // 0 : 5004 (4-aligned)
        const int nc   = h ? (K0A - 5004) : 5004;    // 5236 : 5004 cols (incl. h=1 pads)
        const int lim  = ng * 3;                     // 5004 : 4995 (c0+lim == BOUT for h=1)
        const int t = threadIdx.x;
#pragma unroll
        for (int i = t; i < 1280; i += 256)          // zero 5120 floats
            *(float4*)&smem[i * 4] = float4{0.f, 0.f, 0.f, 0.f};
        __syncthreads();
#pragma unroll
        for (int p = t; p < 512; p += 256) {
            float m = mz[(size_t)spec * 512 + p];
            float v = inten[(size_t)spec * 512 + p];
            bool mask = (m >= 0.0f) && (m < 1000.0f);
            int idx = (int)(m / 0.01f);       // IEEE div + trunc, matches astype(int32)
            idx = min(max(idx, 0), 99999);
            if (mask && idx < 99990) {
                int g = idx / 30;
                if (g >= g0 && g < g0 + ng) {
                    float val = sqrtf(v);         // inten ** 0.5
                    const float* w = bw + (size_t)idx * 3;
                    int l = (g - g0) * 3;
                    atomicAdd(&smem[l + 0], val * w[0]);
                    atomicAdd(&smem[l + 1], val * w[1]);
                    atomicAdd(&smem[l + 2], val * w[2]);
                }
            }
        }
        __syncthreads();
        bf16* Arow = A + (size_t)spec * K0A;
        for (int ch = t; ch * 4 < nc; ch += 256) {
            int lc = ch * 4;
            int c  = c0 + lc;
            bf16 o[4];
#pragma unroll
            for (int e = 0; e < 4; ++e) {
                int l = lc + e;
                o[e] = (bf16)((l < lim) ? (bb[c + e] + smem[l]) : 0.f);
            }
            *(ushort4*)&Arow[c] = *(ushort4*)o;
        }
    } else if (b < 4176) {                // zero K-pad cols 896..1023 of H1b/H2b
        int idx = b - 4144;               // 0..31
        bf16* H = (idx < 16) ? H1b : H2b;
        int sub = idx & 15;
        int t = threadIdx.x;
#pragma unroll
        for (int q = 0; q < 2; ++q) {
            int row = sub * 32 + q * 16 + (t >> 4);
            int col = 896 + (t & 15) * 8;
            *(uint4*)&H[(size_t)row * 1024 + col] = uint4{0u, 0u, 0u, 0u};
        }
    } else {                              // zero cosine accumulators + done counter
        for (int i = threadIdx.x; i < 1024; i += 256) psums[i] = 0.f;
    }
}

// ---------------- GEMM0 (R5-exact) ----------------
__global__ __launch_bounds__(512) void gemm0_splitk(const bf16* __restrict__ A,
                                                    const bf16* __restrict__ Bt,
                                                    bf16* __restrict__ Cslab) {
    constexpr int K0 = K0A, KITERS = 10, BK = 64;
    __shared__ __align__(16) bf16 As[2][128 * BK];   // 16 KB each buf
    __shared__ __align__(16) bf16 Bs[2][128 * BK];   // 16 KB each buf
    const int bid = blockIdx.x;
    const int kp = bid & 15;                  // XCD = bid%8 hosts kp, kp+8
    const int tile = bid >> 4;                // 0..31
    const int mt = tile & 3, nt = tile >> 2;  // 4 x 8
    const int tid = threadIdx.x, wave = tid >> 6, lane = tid & 63;
    const int wm = wave & 1, wn = wave >> 1;  // 2x4 wave grid: 64m x 32n per wave
    const int lrow = lane & 15, quad = lane >> 4;

    const bf16* Ag = A  + (size_t)(mt * 128) * K0 + kp * (KITERS * BK);
    const bf16* Bg = Bt + (size_t)(nt * 128) * K0 + kp * (KITERS * BK);

    auto stage = [&](int buf, int kk) {
        const int k = kk * BK;
        const int lr = lane >> 3;
        const int lch = lane & 7;
#pragma unroll
        for (int j = 0; j < 2; ++j) {                  // A: 128 rows in 2 calls/wave
            int row0 = j * 64 + wave * 8;
            int row = row0 + lr;
            int ch  = lch ^ (row & 7);
            gload_lds16(Ag + (size_t)row * K0 + k + ch * 8, &As[buf][row0 * BK]);
        }
#pragma unroll
        for (int j = 0; j < 2; ++j) {                  // B: 128 rows in 2 calls/wave
            int row0 = j * 64 + wave * 8;
            int row = row0 + lr;
            int ch  = lch ^ (row & 7);
            gload_lds16(Bg + (size_t)row * K0 + k + ch * 8, &Bs[buf][row0 * BK]);
        }
    };

    f32x4 acc[4][2] = {};
    stage(0, 0);
    for (int kk = 0; kk < KITERS; ++kk) {
        const int cur = kk & 1;
        __syncthreads();                      // buf[cur] drained (vmcnt0 at barrier)
        if (kk + 1 < KITERS) stage(cur ^ 1, kk + 1);  // prefetch overlaps compute
#pragma unroll
        for (int ks = 0; ks < 2; ++ks) {
            bf16x8 af[4], bfr[2];
            const int c = ks * 4 + quad;
#pragma unroll
            for (int im = 0; im < 4; ++im) {
                int r = wm * 64 + im * 16 + lrow;
                af[im] = *(const bf16x8*)&As[cur][r * BK + ((c ^ (r & 7)) << 3)];
            }
#pragma unroll
            for (int in = 0; in < 2; ++in) {
                int r = wn * 32 + in * 16 + lrow;
                bfr[in] = *(const bf16x8*)&Bs[cur][r * BK + ((c ^ (r & 7)) << 3)];
            }
#pragma unroll
            for (int im = 0; im < 4; ++im)
#pragma unroll
                for (int in = 0; in < 2; ++in)
                    acc[im][in] = __builtin_amdgcn_mfma_f32_16x16x32_bf16(af[im], bfr[in], acc[im][in], 0, 0, 0);
        }
    }
    // bf16 partial stores into this kp's slab — no atomics, no fences
    bf16* C = Cslab + (size_t)kp * (NSPEC * N00);
#pragma unroll
    for (int im = 0; im < 4; ++im) {
        int row0 = mt * 128 + wm * 64 + im * 16 + quad * 4;
#pragma unroll
        for (int in = 0; in < 2; ++in) {
            int col = nt * 128 + wn * 32 + in * 16 + lrow;
#pragma unroll
            for (int r = 0; r < 4; ++r)
                C[(size_t)(row0 + r) * N00 + col] = (bf16)acc[im][in][r];
        }
    }
}

// ---------------- reduce 16 bf16 slabs + bias + relu + bf16 cvt (R5-exact) ----------------
__global__ __launch_bounds__(256) void reduce_bias_relu(const bf16* __restrict__ Cslab,
                                                        const float* __restrict__ b0,
                                                        bf16* __restrict__ H0b) {
    int idx = blockIdx.x * 256 + threadIdx.x;     // 65536 chunks of 8
    int r = idx >> 7, c = (idx & 127) * 8;
    float s[8] = {};
#pragma unroll
    for (int kp = 0; kp < KSPLIT0; ++kp) {
        bf16x8 v = *(const bf16x8*)&Cslab[(size_t)kp * (NSPEC * N00) + (size_t)r * N00 + c];
#pragma unroll
        for (int j = 0; j < 8; ++j) s[j] += (float)v[j];
    }
    bf16 o[8];
#pragma unroll
    for (int j = 0; j < 8; ++j)
        o[j] = (bf16)fmaxf(s[j] + ((c + j < 1000) ? b0[c + j] : 0.f), 0.f);
    *(uint4*)&H0b[(size_t)r * N00 + c] = *(uint4*)o;
}

// ---------------- tail GEMM (R5-exact): 32x64 tiles, BK=256, full-K per wave ----------------
template <bool LAST>
__global__ __launch_bounds__(512) void gemm_tail(const bf16* __restrict__ A,
                                                 const bf16* __restrict__ Bt,
                                                 const float* __restrict__ bias,
                                                 bf16* __restrict__ Ob,
                                                 float* __restrict__ psums,
                                                 unsigned* __restrict__ done,
                                                 float* __restrict__ out,
                                                 int Nreal, int ntiles) {
    constexpr int BK = 256, KITERS = 4;
    __shared__ __align__(16) bf16 As[2][32 * BK];   // 16 KB each
    __shared__ __align__(16) bf16 Bs[2][64 * BK];   // 32 KB each
    __shared__ unsigned lastf;
    const int bid = blockIdx.x;
    const int mt = bid / ntiles, nt = bid % ntiles;
    const int tid = threadIdx.x, wave = tid >> 6, lane = tid & 63;
    const int wm = wave & 1, wn = wave >> 1;        // 2(m) x 4(n) waves over 32x64
    const int lrow = lane & 15, quad = lane >> 4;

    const bf16* Ag = A  + (size_t)(mt * 32) * 1024;
    const bf16* Bg = Bt + (size_t)(nt * 64) * 1024;

    auto stage = [&](int buf, int kk) {
        const int k = kk * BK;
#pragma unroll
        for (int j = 0; j < 2; ++j) {                  // A: 32 rows, 2 calls/wave
            int row0 = (wave + j * 8) * 2;
            int row = row0 + (lane >> 5);
            int ch  = (lane & 31) ^ (row & 31);        // swizzled source chunk
            gload_lds16(Ag + (size_t)row * 1024 + k + ch * 8, &As[buf][row0 * BK]);
        }
#pragma unroll
        for (int j = 0; j < 4; ++j) {                  // B: 64 rows, 4 calls/wave
            int row0 = (wave + j * 8) * 2;
            int row = row0 + (lane >> 5);
            int ch  = (lane & 31) ^ (row & 31);
            gload_lds16(Bg + (size_t)row * 1024 + k + ch * 8, &Bs[buf][row0 * BK]);
        }
    };

    f32x4 acc = {};
    stage(0, 0);
    for (int kk = 0; kk < KITERS; ++kk) {
        const int cur = kk & 1;
        __syncthreads();
        if (kk + 1 < KITERS) stage(cur ^ 1, kk + 1);
#pragma unroll
        for (int ks = 0; ks < 8; ++ks) {               // full K: 8 MFMA per iter per wave
            int ra = wm * 16 + lrow, rb = wn * 16 + lrow;
            int c = ks * 4 + quad;                     // c 0..31 covers BK=256
            bf16x8 af  = *(const bf16x8*)&As[cur][ra * BK + ((c ^ (ra & 31)) << 3)];
            bf16x8 bfr = *(const bf16x8*)&Bs[cur][rb * BK + ((c ^ (rb & 31)) << 3)];
            acc = __builtin_amdgcn_mfma_f32_16x16x32_bf16(af, bfr, acc, 0, 0, 0);
        }
    }
    // epilogue: each wave owns quadrant (wm, wn) — exactly-once coverage of 32x64
    {
        int row0 = mt * 32 + wm * 16 + quad * 4;
        int col  = nt * 64 + wn * 16 + lrow;
        if (!LAST) {
            float bv = (col < Nreal) ? bias[col] : 0.f;
#pragma unroll
            for (int r = 0; r < 4; ++r)
                Ob[(size_t)(row0 + r) * 1024 + col] = (bf16)fmaxf(acc[r] + bv, 0.f);
        } else {
            bool valid = (col < 400);
            float bv = valid ? bias[col] : 0.f;
            float v[4];
#pragma unroll
            for (int r = 0; r < 4; ++r) v[r] = valid ? (acc[r] + bv) : 0.f;
            int p0 = row0 >> 1;                        // pairs p0, p0+1 (row0 even)
            float sums[6] = {v[0] * v[1], v[0] * v[0], v[1] * v[1],
                             v[2] * v[3], v[2] * v[2], v[3] * v[3]};
#pragma unroll
            for (int off = 1; off < 16; off <<= 1)
#pragma unroll
                for (int s = 0; s < 6; ++s) sums[s] += __shfl_xor(sums[s], off);
            if (lrow == 0) {
#pragma unroll
                for (int s = 0; s < 3; ++s) {
                    atomicAdd(&psums[(p0 + 0) * 3 + s], sums[s]);
                    atomicAdd(&psums[(p0 + 1) * 3 + s], sums[3 + s]);
                }
            }
        }
    }
    if (LAST) {
        // last-finisher cosine finalize (112 blocks)
        __syncthreads();
        if (tid == 0) {
            __threadfence();               // release: psum atomics ordered before counter add
            unsigned old = __hip_atomic_fetch_add(done, 1u, __ATOMIC_ACQ_REL,
                                                  __HIP_MEMORY_SCOPE_AGENT);
            lastf = (old == 111u) ? 1u : 0u;
        }
        __syncthreads();
        if (lastf && tid < 256) {
            float d  = __hip_atomic_load(&psums[tid * 3 + 0], __ATOMIC_RELAXED, __HIP_MEMORY_SCOPE_AGENT);
            float s1 = __hip_atomic_load(&psums[tid * 3 + 1], __ATOMIC_RELAXED, __HIP_MEMORY_SCOPE_AGENT);
            float s2 = __hip_atomic_load(&psums[tid * 3 + 2], __ATOMIC_RELAXED, __HIP_MEMORY_SCOPE_AGENT);
            float n1 = fmaxf(sqrtf(s1), 1e-6f);
            float n2 = fmaxf(sqrtf(s2), 1e-6f);
            out[tid] = d / (n1 * n2);
        }
    }
}

extern "C" void kernel_launch(void* const* d_in, const int* in_sizes, int n_in,
                              void* d_out, int out_size, void* d_ws, size_t ws_size,
                              hipStream_t stream) {
    const float* mz    = (const float*)d_in[0];
    const float* inten = (const float*)d_in[1];
    const float* bw    = (const float*)d_in[2];
    const float* bb    = (const float*)d_in[3];
    const float* w0    = (const float*)d_in[4];
    const float* b0    = (const float*)d_in[5];
    const float* w1    = (const float*)d_in[6];
    const float* b1    = (const float*)d_in[7];
    const float* w2    = (const float*)d_in[8];
    const float* b2    = (const float*)d_in[9];
    const float* we    = (const float*)d_in[10];
    const float* be    = (const float*)d_in[11];
    float* out = (float*)d_out;

    char* ws = (char*)d_ws;
    size_t off = 0;
    auto alloc = [&](size_t bytes) { char* p = ws + off; off += (bytes + 255) & ~(size_t)255; return p; };
    bf16*  A     = (bf16*) alloc((size_t)NSPEC * K0A * 2);
    bf16*  B0t   = (bf16*) alloc((size_t)N00 * K0A * 2);
    bf16*  B1t   = (bf16*) alloc((size_t)896 * 1024 * 2);
    bf16*  B2t   = (bf16*) alloc((size_t)896 * 1024 * 2);
    bf16*  BEt   = (bf16*) alloc((size_t)448 * 1024 * 2);
    bf16*  Cslab = (bf16*) alloc((size_t)KSPLIT0 * NSPEC * N00 * 2);   // 16 MB
    bf16*  H0b   = (bf16*) alloc((size_t)NSPEC * 1024 * 2);
    bf16*  H1b   = (bf16*) alloc((size_t)NSPEC * 1024 * 2);
    bf16*  H2b   = (bf16*) alloc((size_t)NSPEC * 1024 * 2);
    float* psums = (float*)alloc(1024 * 4);        // 768 psums + done counter + pad
    unsigned* done = (unsigned*)(psums + 768);

    // 1: prep v2 — 256-thr/20KB blocks, 8/CU occupancy (R9 PMC: was rounds-bound at 4/CU)
    prep_all<<<4177, 256, 0, stream>>>(mz, inten, bw, bb, w0, w1, w2, we,
                                       A, B0t, B1t, B2t, BEt, H1b, H2b, psums);
    // 2: big GEMM, 128x128 tiles, split-K=16 XCD-pinned, swizzled LDS, bf16 slab stores
    gemm0_splitk<<<512, 512, 0, stream>>>(A, B0t, Cslab);
    // 3: slab reduce + bias + relu + bf16 cvt
    reduce_bias_relu<<<256, 256, 0, stream>>>(Cslab, b0, H0b);
    // 4-5: tail GEMMs, 32x64 tiles, full-K waves (bias+relu+bf16 fused)
    gemm_tail<false><<<224, 512, 0, stream>>>(H0b, B1t, b1, H1b, nullptr, nullptr, nullptr, 800, 14);
    gemm_tail<false><<<224, 512, 0, stream>>>(H1b, B2t, b2, H2b, nullptr, nullptr, nullptr, 800, 14);
    // 6: last GEMM + cosine partials + last-finisher finalize
    gemm_tail<true ><<<112, 512, 0, stream>>>(H2b, BEt, be, nullptr, psums, done, out, 400, 7);
}

// Round 11
// 163.652 us; speedup vs baseline: 1.9732x; 1.0326x over previous
//
#include <hip/hip_runtime.h>

typedef __bf16 bf16;
typedef __bf16 bf16x8 __attribute__((ext_vector_type(8)));
typedef float  f32x4  __attribute__((ext_vector_type(4)));

// Problem constants
#define NSPEC   512          // 256 pairs * 2
#define BOUT    9999         // GROUPS*3
#define K0A     10240        // BOUT padded to 16*10*64 (ksplit*kiters*BK)
#define N00     1024         // 1000 padded
#define KSPLIT0 16

// async global->LDS, 16B per lane; lds base must be wave-uniform (HW adds lane*16)
__device__ __forceinline__ void gload_lds16(const bf16* g, bf16* l) {
    auto* gp = reinterpret_cast<const __attribute__((address_space(1))) unsigned int*>(
        reinterpret_cast<uintptr_t>(g));
    auto* lp = reinterpret_cast<__attribute__((address_space(3))) unsigned int*>(
        reinterpret_cast<uintptr_t>(l));
    __builtin_amdgcn_global_load_lds(gp, lp, 16, 0, 0);
}

// ---------------- transpose helper: 64(n) x 64(k) tile, 512 threads (R5-verified) ----------------
__device__ __forceinline__ void transpose_tile64(const float* __restrict__ src,
                                                 bf16* __restrict__ dst,
                                                 int K, int N, int K0,
                                                 float* tile, int bx, int by) {
    int n0 = bx * 64, k0 = by * 64;
    int t = threadIdx.x;
    {
        int kr = t >> 3, fc = (t & 7) * 8;           // 64 k-rows x 64 n-cols, 8 f32/thread
        int gk = k0 + kr;
#pragma unroll
        for (int h = 0; h < 2; ++h) {
            int gn = n0 + fc + h * 4;
            float4 v;
            if (gk < K && gn + 3 < N) {              // interior fast path (N%4==0 -> aligned)
                v = *reinterpret_cast<const float4*>(src + (size_t)gk * N + gn);
            } else {
                v.x = (gk < K && gn + 0 < N) ? src[(size_t)gk * N + gn + 0] : 0.f;
                v.y = (gk < K && gn + 1 < N) ? src[(size_t)gk * N + gn + 1] : 0.f;
                v.z = (gk < K && gn + 2 < N) ? src[(size_t)gk * N + gn + 2] : 0.f;
                v.w = (gk < K && gn + 3 < N) ? src[(size_t)gk * N + gn + 3] : 0.f;
            }
            tile[kr * 65 + fc + h * 4 + 0] = v.x;
            tile[kr * 65 + fc + h * 4 + 1] = v.y;
            tile[kr * 65 + fc + h * 4 + 2] = v.z;
            tile[kr * 65 + fc + h * 4 + 3] = v.w;
        }
    }
    __syncthreads();
    {
        int nr = t >> 3, kc = (t & 7) * 8;           // 64 n-rows x 64 k-cols, 8 bf16/thread
        bf16 v[8];
#pragma unroll
        for (int e = 0; e < 8; ++e) v[e] = (bf16)tile[(kc + e) * 65 + nr];  // 2-way banks: free
        *(uint4*)&dst[(size_t)(n0 + nr) * K0 + k0 + kc] = *(uint4*)v;       // 16 B store
    }
}

// ---------------- mega-prep (R5-exact): transposes + build_A + pads + psums/done ----------------
// Block map (3665 blocks): w0 2560 | w1 224 | w2 224 | we 112 | build_A 512 | pads 32 | psums 1
__global__ __launch_bounds__(512) void prep_all(const float* __restrict__ mz,
                                                const float* __restrict__ inten,
                                                const float* __restrict__ bw,
                                                const float* __restrict__ bb,
                                                const float* __restrict__ w0,
                                                const float* __restrict__ w1,
                                                const float* __restrict__ w2,
                                                const float* __restrict__ we,
                                                bf16* __restrict__ A,
                                                bf16* __restrict__ B0t,
                                                bf16* __restrict__ B1t,
                                                bf16* __restrict__ B2t,
                                                bf16* __restrict__ BEt,
                                                bf16* __restrict__ H1b,
                                                bf16* __restrict__ H2b,
                                                float* __restrict__ psums) {
    __shared__ float smem[K0A];    // 40 KB: sacc for build_A, tile[64*65] for transposes
    int b = blockIdx.x;
    if (b < 2560) {                       // w0 -> B0t (1024 x 10240): 16(n) x 160(k) tiles
        transpose_tile64(w0, B0t, BOUT, 1000, K0A, smem, b & 15, b >> 4);
    } else if (b < 2784) {                // w1 -> B1t (896 x 1024): 14 x 16
        int r = b - 2560;
        transpose_tile64(w1, B1t, 1000, 800, 1024, smem, r % 14, r / 14);
    } else if (b < 3008) {                // w2 -> B2t (896 x 1024): 14 x 16
        int r = b - 2784;
        transpose_tile64(w2, B2t, 800, 800, 1024, smem, r % 14, r / 14);
    } else if (b < 3120) {                // we -> BEt (448 x 1024): 7 x 16
        int r = b - 3008;
        transpose_tile64(we, BEt, 800, 400, 1024, smem, r % 7, r / 7);
    } else if (b < 3632) {                // build_A: one block per spectrum
        const int spec = b - 3120;
        const int t = threadIdx.x;
#pragma unroll
        for (int i = 0; i < 5; ++i)
            *(float4*)&smem[(i * 512 + t) * 4] = float4{0.f, 0.f, 0.f, 0.f};
        __syncthreads();
        {
            float m = mz[(size_t)spec * 512 + t];
            float v = inten[(size_t)spec * 512 + t];
            bool mask = (m >= 0.0f) && (m < 1000.0f);
            int idx = (int)(m / 0.01f);       // IEEE div + trunc, matches astype(int32)
            idx = min(max(idx, 0), 99999);
            if (mask && idx < 99990) {
                int g = idx / 30;
                float val = sqrtf(v);         // inten ** 0.5
                const float* w = bw + (size_t)idx * 3;
                atomicAdd(&smem[g * 3 + 0], val * w[0]);
                atomicAdd(&smem[g * 3 + 1], val * w[1]);
                atomicAdd(&smem[g * 3 + 2], val * w[2]);
            }
        }
        __syncthreads();
        bf16* Arow = A + (size_t)spec * K0A;
#pragma unroll
        for (int i = 0; i < 5; ++i) {
            int c = (i * 512 + t) * 4;
            float4 s = *(const float4*)&smem[c];
            bf16 o[4];
            o[0] = (bf16)((c + 0 < BOUT) ? bb[c + 0] + s.x : 0.f);
            o[1] = (bf16)((c + 1 < BOUT) ? bb[c + 1] + s.y : 0.f);
            o[2] = (bf16)((c + 2 < BOUT) ? bb[c + 2] + s.z : 0.f);
            o[3] = (bf16)((c + 3 < BOUT) ? bb[c + 3] + s.w : 0.f);
            *(ushort4*)&Arow[c] = *(ushort4*)o;
        }
    } else if (b < 3664) {                // zero K-pad cols 896..1023 of H1b/H2b
        int idx = b - 3632;               // 0..31
        bf16* H = (idx < 16) ? H1b : H2b;
        int sub = idx & 15;
        int t = threadIdx.x;
        int row = sub * 32 + (t >> 4);
        int col = 896 + (t & 15) * 8;
        *(uint4*)&H[(size_t)row * 1024 + col] = uint4{0u, 0u, 0u, 0u};
    } else {                              // zero cosine accumulators + done counter
        for (int i = threadIdx.x; i < 1024; i += 512) psums[i] = 0.f;
    }
}

// ---------------- GEMM0 (R5-exact): 128x128xBK64, split-K=16 XCD-pinned, dbuf, swizzled ----------------
__global__ __launch_bounds__(512) void gemm0_splitk(const bf16* __restrict__ A,
                                                    const bf16* __restrict__ Bt,
                                                    bf16* __restrict__ Cslab) {
    constexpr int K0 = K0A, KITERS = 10, BK = 64;
    __shared__ __align__(16) bf16 As[2][128 * BK];   // 16 KB each buf
    __shared__ __align__(16) bf16 Bs[2][128 * BK];   // 16 KB each buf
    const int bid = blockIdx.x;
    const int kp = bid & 15;                  // XCD = bid%8 hosts kp, kp+8
    const int tile = bid >> 4;                // 0..31
    const int mt = tile & 3, nt = tile >> 2;  // 4 x 8
    const int tid = threadIdx.x, wave = tid >> 6, lane = tid & 63;
    const int wm = wave & 1, wn = wave >> 1;  // 2x4 wave grid: 64m x 32n per wave
    const int lrow = lane & 15, quad = lane >> 4;

    const bf16* Ag = A  + (size_t)(mt * 128) * K0 + kp * (KITERS * BK);
    const bf16* Bg = Bt + (size_t)(nt * 128) * K0 + kp * (KITERS * BK);

    auto stage = [&](int buf, int kk) {
        const int k = kk * BK;
        const int lr = lane >> 3;
        const int lch = lane & 7;
#pragma unroll
        for (int j = 0; j < 2; ++j) {                  // A: 128 rows in 2 calls/wave
            int row0 = j * 64 + wave * 8;
            int row = row0 + lr;
            int ch  = lch ^ (row & 7);
            gload_lds16(Ag + (size_t)row * K0 + k + ch * 8, &As[buf][row0 * BK]);
        }
#pragma unroll
        for (int j = 0; j < 2; ++j) {                  // B: 128 rows in 2 calls/wave
            int row0 = j * 64 + wave * 8;
            int row = row0 + lr;
            int ch  = lch ^ (row & 7);
            gload_lds16(Bg + (size_t)row * K0 + k + ch * 8, &Bs[buf][row0 * BK]);
        }
    };

    f32x4 acc[4][2] = {};
    stage(0, 0);
    for (int kk = 0; kk < KITERS; ++kk) {
        const int cur = kk & 1;
        __syncthreads();                      // buf[cur] drained (vmcnt0 at barrier)
        if (kk + 1 < KITERS) stage(cur ^ 1, kk + 1);  // prefetch overlaps compute
#pragma unroll
        for (int ks = 0; ks < 2; ++ks) {
            bf16x8 af[4], bfr[2];
            const int c = ks * 4 + quad;
#pragma unroll
            for (int im = 0; im < 4; ++im) {
                int r = wm * 64 + im * 16 + lrow;
                af[im] = *(const bf16x8*)&As[cur][r * BK + ((c ^ (r & 7)) << 3)];
            }
#pragma unroll
            for (int in = 0; in < 2; ++in) {
                int r = wn * 32 + in * 16 + lrow;
                bfr[in] = *(const bf16x8*)&Bs[cur][r * BK + ((c ^ (r & 7)) << 3)];
            }
#pragma unroll
            for (int im = 0; im < 4; ++im)
#pragma unroll
                for (int in = 0; in < 2; ++in)
                    acc[im][in] = __builtin_amdgcn_mfma_f32_16x16x32_bf16(af[im], bfr[in], acc[im][in], 0, 0, 0);
        }
    }
    // bf16 partial stores into this kp's slab — no atomics, no fences
    bf16* C = Cslab + (size_t)kp * (NSPEC * N00);
#pragma unroll
    for (int im = 0; im < 4; ++im) {
        int row0 = mt * 128 + wm * 64 + im * 16 + quad * 4;
#pragma unroll
        for (int in = 0; in < 2; ++in) {
            int col = nt * 128 + wn * 32 + in * 16 + lrow;
#pragma unroll
            for (int r = 0; r < 4; ++r)
                C[(size_t)(row0 + r) * N00 + col] = (bf16)acc[im][in][r];
        }
    }
}

// ---------------- reduce 16 bf16 slabs + bias + relu + bf16 cvt (R5-exact) ----------------
__global__ __launch_bounds__(256) void reduce_bias_relu(const bf16* __restrict__ Cslab,
                                                        const float* __restrict__ b0,
                                                        bf16* __restrict__ H0b) {
    int idx = blockIdx.x * 256 + threadIdx.x;     // 65536 chunks of 8
    int r = idx >> 7, c = (idx & 127) * 8;
    float s[8] = {};
#pragma unroll
    for (int kp = 0; kp < KSPLIT0; ++kp) {
        bf16x8 v = *(const bf16x8*)&Cslab[(size_t)kp * (NSPEC * N00) + (size_t)r * N00 + c];
#pragma unroll
        for (int j = 0; j < 8; ++j) s[j] += (float)v[j];
    }
    bf16 o[8];
#pragma unroll
    for (int j = 0; j < 8; ++j)
        o[j] = (bf16)fmaxf(s[j] + ((c + j < 1000) ? b0[c + j] : 0.f), 0.f);
    *(uint4*)&H0b[(size_t)r * N00 + c] = *(uint4*)o;
}

// ---------------- tail GEMM (R5-exact): 32x64 tiles, BK=256, full-K per wave ----------------
template <bool LAST>
__global__ __launch_bounds__(512) void gemm_tail(const bf16* __restrict__ A,
                                                 const bf16* __restrict__ Bt,
                                                 const float* __restrict__ bias,
                                                 bf16* __restrict__ Ob,
                                                 float* __restrict__ psums,
                                                 unsigned* __restrict__ done,
                                                 float* __restrict__ out,
                                                 int Nreal, int ntiles) {
    constexpr int BK = 256, KITERS = 4;
    __shared__ __align__(16) bf16 As[2][32 * BK];   // 16 KB each
    __shared__ __align__(16) bf16 Bs[2][64 * BK];   // 32 KB each
    __shared__ unsigned lastf;
    const int bid = blockIdx.x;
    const int mt = bid / ntiles, nt = bid % ntiles;
    const int tid = threadIdx.x, wave = tid >> 6, lane = tid & 63;
    const int wm = wave & 1, wn = wave >> 1;        // 2(m) x 4(n) waves over 32x64
    const int lrow = lane & 15, quad = lane >> 4;

    const bf16* Ag = A  + (size_t)(mt * 32) * 1024;
    const bf16* Bg = Bt + (size_t)(nt * 64) * 1024;

    auto stage = [&](int buf, int kk) {
        const int k = kk * BK;
#pragma unroll
        for (int j = 0; j < 2; ++j) {                  // A: 32 rows, 2 calls/wave
            int row0 = (wave + j * 8) * 2;
            int row = row0 + (lane >> 5);
            int ch  = (lane & 31) ^ (row & 31);        // swizzled source chunk
            gload_lds16(Ag + (size_t)row * 1024 + k + ch * 8, &As[buf][row0 * BK]);
        }
#pragma unroll
        for (int j = 0; j < 4; ++j) {                  // B: 64 rows, 4 calls/wave
            int row0 = (wave + j * 8) * 2;
            int row = row0 + (lane >> 5);
            int ch  = (lane & 31) ^ (row & 31);
            gload_lds16(Bg + (size_t)row * 1024 + k + ch * 8, &Bs[buf][row0 * BK]);
        }
    };

    f32x4 acc = {};
    stage(0, 0);
    for (int kk = 0; kk < KITERS; ++kk) {
        const int cur = kk & 1;
        __syncthreads();
        if (kk + 1 < KITERS) stage(cur ^ 1, kk + 1);
#pragma unroll
        for (int ks = 0; ks < 8; ++ks) {               // full K: 8 MFMA per iter per wave
            int ra = wm * 16 + lrow, rb = wn * 16 + lrow;
            int c = ks * 4 + quad;                     // c 0..31 covers BK=256
            bf16x8 af  = *(const bf16x8*)&As[cur][ra * BK + ((c ^ (ra & 31)) << 3)];
            bf16x8 bfr = *(const bf16x8*)&Bs[cur][rb * BK + ((c ^ (rb & 31)) << 3)];
            acc = __builtin_amdgcn_mfma_f32_16x16x32_bf16(af, bfr, acc, 0, 0, 0);
        }
    }
    // epilogue: each wave owns quadrant (wm, wn) — exactly-once coverage of 32x64
    {
        int row0 = mt * 32 + wm * 16 + quad * 4;
        int col  = nt * 64 + wn * 16 + lrow;
        if (!LAST) {
            float bv = (col < Nreal) ? bias[col] : 0.f;
#pragma unroll
            for (int r = 0; r < 4; ++r)
                Ob[(size_t)(row0 + r) * 1024 + col] = (bf16)fmaxf(acc[r] + bv, 0.f);
        } else {
            bool valid = (col < 400);
            float bv = valid ? bias[col] : 0.f;
            float v[4];
#pragma unroll
            for (int r = 0; r < 4; ++r) v[r] = valid ? (acc[r] + bv) : 0.f;
            int p0 = row0 >> 1;                        // pairs p0, p0+1 (row0 even)
            float sums[6] = {v[0] * v[1], v[0] * v[0], v[1] * v[1],
                             v[2] * v[3], v[2] * v[2], v[3] * v[3]};
#pragma unroll
            for (int off = 1; off < 16; off <<= 1)
#pragma unroll
                for (int s = 0; s < 6; ++s) sums[s] += __shfl_xor(sums[s], off);
            if (lrow == 0) {
#pragma unroll
                for (int s = 0; s < 3; ++s) {
                    atomicAdd(&psums[(p0 + 0) * 3 + s], sums[s]);
                    atomicAdd(&psums[(p0 + 1) * 3 + s], sums[3 + s]);
                }
            }
        }
    }
    if (LAST) {
        // last-finisher cosine finalize (112 blocks)
        __syncthreads();
        if (tid == 0) {
            __threadfence();               // release: psum atomics ordered before counter add
            unsigned old = __hip_atomic_fetch_add(done, 1u, __ATOMIC_ACQ_REL,
                                                  __HIP_MEMORY_SCOPE_AGENT);
            lastf = (old == 111u) ? 1u : 0u;
        }
        __syncthreads();
        if (lastf && tid < 256) {
            float d  = __hip_atomic_load(&psums[tid * 3 + 0], __ATOMIC_RELAXED, __HIP_MEMORY_SCOPE_AGENT);
            float s1 = __hip_atomic_load(&psums[tid * 3 + 1], __ATOMIC_RELAXED, __HIP_MEMORY_SCOPE_AGENT);
            float s2 = __hip_atomic_load(&psums[tid * 3 + 2], __ATOMIC_RELAXED, __HIP_MEMORY_SCOPE_AGENT);
            float n1 = fmaxf(sqrtf(s1), 1e-6f);
            float n2 = fmaxf(sqrtf(s2), 1e-6f);
            out[tid] = d / (n1 * n2);
        }
    }
}

extern "C" void kernel_launch(void* const* d_in, const int* in_sizes, int n_in,
                              void* d_out, int out_size, void* d_ws, size_t ws_size,
                              hipStream_t stream) {
    const float* mz    = (const float*)d_in[0];
    const float* inten = (const float*)d_in[1];
    const float* bw    = (const float*)d_in[2];
    const float* bb    = (const float*)d_in[3];
    const float* w0    = (const float*)d_in[4];
    const float* b0    = (const float*)d_in[5];
    const float* w1    = (const float*)d_in[6];
    const float* b1    = (const float*)d_in[7];
    const float* w2    = (const float*)d_in[8];
    const float* b2    = (const float*)d_in[9];
    const float* we    = (const float*)d_in[10];
    const float* be    = (const float*)d_in[11];
    float* out = (float*)d_out;

    char* ws = (char*)d_ws;
    size_t off = 0;
    auto alloc = [&](size_t bytes) { char* p = ws + off; off += (bytes + 255) & ~(size_t)255; return p; };
    bf16*  A     = (bf16*) alloc((size_t)NSPEC * K0A * 2);
    bf16*  B0t   = (bf16*) alloc((size_t)N00 * K0A * 2);
    bf16*  B1t   = (bf16*) alloc((size_t)896 * 1024 * 2);
    bf16*  B2t   = (bf16*) alloc((size_t)896 * 1024 * 2);
    bf16*  BEt   = (bf16*) alloc((size_t)448 * 1024 * 2);
    bf16*  Cslab = (bf16*) alloc((size_t)KSPLIT0 * NSPEC * N00 * 2);   // 16 MB
    bf16*  H0b   = (bf16*) alloc((size_t)NSPEC * 1024 * 2);
    bf16*  H1b   = (bf16*) alloc((size_t)NSPEC * 1024 * 2);
    bf16*  H2b   = (bf16*) alloc((size_t)NSPEC * 1024 * 2);
    float* psums = (float*)alloc(1024 * 4);        // 768 psums + done counter + pad
    unsigned* done = (unsigned*)(psums + 768);

    // R5-exact pipeline — session best (162.26 us). Budget (R6/R8/R9 probes): fixed 94.8,
    // prep 12.8 (~BW floor), gemm0 14.7 (728 TF eff), reduce+t1+t2 10.1, t3 ~2.5,
    // boundaries ~22-27 (cheaper than all tested fusion alternatives).
    prep_all<<<3665, 512, 0, stream>>>(mz, inten, bw, bb, w0, w1, w2, we,
                                       A, B0t, B1t, B2t, BEt, H1b, H2b, psums);
    gemm0_splitk<<<512, 512, 0, stream>>>(A, B0t, Cslab);
    reduce_bias_relu<<<256, 256, 0, stream>>>(Cslab, b0, H0b);
    gemm_tail<false><<<224, 512, 0, stream>>>(H0b, B1t, b1, H1b, nullptr, nullptr, nullptr, 800, 14);
    gemm_tail<false><<<224, 512, 0, stream>>>(H1b, B2t, b2, H2b, nullptr, nullptr, nullptr, 800, 14);
    gemm_tail<true ><<<112, 512, 0, stream>>>(H2b, BEt, be, nullptr, psums, done, out, 400, 7);
}